// Round 2
// baseline (193.474 us; speedup 1.0000x reference)
//
#include <hip/hip_runtime.h>
#include <hip/hip_bf16.h>

// out[o,i,h,w] = sum_k weights[o,i,k] * x[k,h,w]
// weights: (2048, 2048, 3) fp32   x: (3, 3, 3) fp32   out: (2048, 2048, 3, 3) fp32
//
// Memory-bound: 50.3 MB read + 151 MB write, ~190 MFLOP -> floor ~31 us @ 6.6 TB/s.
// R1 experiment: drop LDS staging + barrier; direct contiguous 36 B/thread stores.
// Wave writes a contiguous 2304 B span across its 3 store insts -> TCC merges lines.

__global__ __launch_bounds__(256) void gf_kernel(const float* __restrict__ x,
                                                 const float* __restrict__ w,
                                                 float* __restrict__ out) {
    const unsigned p = blockIdx.x * 256u + threadIdx.x;   // pair index (o*2048+i)

    // 3 contiguous weight floats per thread; lanes stride 12 B -> coalesced.
    const float w0 = w[p * 3 + 0];
    const float w1 = w[p * 3 + 1];
    const float w2 = w[p * 3 + 2];

    // x: 27 wave-uniform floats -> scalar loads via constant cache.
    float o[9];
#pragma unroll
    for (int hw = 0; hw < 9; ++hw) {
        o[hw] = w0 * x[hw] + w1 * x[9 + hw] + w2 * x[18 + hw];
    }

    // 36 contiguous bytes per thread, dword-aligned (p*36). Contiguous loop of
    // dword stores; compiler may merge to dwordx4+dwordx4+dword (gfx950 allows
    // dword-aligned multi-dword global access).
    float* __restrict__ dst = out + (size_t)p * 9;
#pragma unroll
    for (int j = 0; j < 9; ++j) {
        dst[j] = o[j];
    }
}

extern "C" void kernel_launch(void* const* d_in, const int* in_sizes, int n_in,
                              void* d_out, int out_size, void* d_ws, size_t ws_size,
                              hipStream_t stream) {
    const float* x = (const float*)d_in[0];   // 27 floats
    const float* w = (const float*)d_in[1];   // 2048*2048*3 floats
    float* out = (float*)d_out;               // 2048*2048*9 floats

    const int pairs = 2048 * 2048;            // 4,194,304
    const int blocks = pairs / 256;           // 16384, exact cover
    gf_kernel<<<blocks, 256, 0, stream>>>(x, w, out);
}

// Round 3
// 187.513 us; speedup vs baseline: 1.0318x; 1.0318x over previous
//
#include <hip/hip_runtime.h>
#include <hip/hip_bf16.h>

// out[o,i,h,w] = sum_k weights[o,i,k] * x[k,h,w]
// weights: (2048, 2048, 3) fp32   x: (3, 3, 3) fp32   out: (2048, 2048, 3, 3) fp32
//
// Memory-bound: 50.3 MB read + 151 MB write -> floor ~31 us @ 6.6 TB/s.
// R3: wave-private LDS staging (no __syncthreads), 4 pairs/thread, exact
// 9-float4/lane flush, b128 LDS writes (bank-stride 4 -> conflict-free).

#define PAIRS_PER_THREAD 4
#define PAIRS_PER_WAVE   (64 * PAIRS_PER_THREAD)          // 256
#define PAIRS_PER_BLOCK  (4 * PAIRS_PER_WAVE)             // 1024 (4 waves)
#define WAVE_SLICE_F     (PAIRS_PER_WAVE * 9)             // 2304 floats = 9216 B

__global__ __launch_bounds__(256) void gf_kernel(const float* __restrict__ x,
                                                 const float* __restrict__ w,
                                                 float* __restrict__ out) {
    __shared__ __align__(16) float so[4 * WAVE_SLICE_F];  // 36,864 B

    const int t    = threadIdx.x;
    const int wave = t >> 6;
    const int lane = t & 63;

    const unsigned wavePair = blockIdx.x * PAIRS_PER_BLOCK + wave * PAIRS_PER_WAVE;
    const unsigned p0       = wavePair + lane * PAIRS_PER_THREAD;  // multiple of 4

    // 12 weight floats = 3 aligned float4 loads (p0*12 B is 16B-aligned).
    const float4* __restrict__ wv = (const float4*)(w + (size_t)p0 * 3);
    const float4 wa = wv[0], wb = wv[1], wc = wv[2];
    const float wreg[12] = {wa.x, wa.y, wa.z, wa.w,
                            wb.x, wb.y, wb.z, wb.w,
                            wc.x, wc.y, wc.z, wc.w};

    // x: 27 wave-uniform floats -> scalar loads via constant path.
    float xr[27];
#pragma unroll
    for (int i = 0; i < 27; ++i) xr[i] = x[i];

    // Compute 36 contiguous output floats (4 pairs x 9), fully in registers.
    float o36[36];
#pragma unroll
    for (int pp = 0; pp < PAIRS_PER_THREAD; ++pp) {
        const float w0 = wreg[pp * 3 + 0];
        const float w1 = wreg[pp * 3 + 1];
        const float w2 = wreg[pp * 3 + 2];
#pragma unroll
        for (int hw = 0; hw < 9; ++hw) {
            o36[pp * 9 + hw] = w0 * xr[hw] + w1 * xr[9 + hw] + w2 * xr[18 + hw];
        }
    }

    // Stage to wave-private LDS slice: 9 x ds_write_b128, lane stride 144 B
    // (dword-bank stride 4 -> lanes tile all 32 banks evenly, conflict-free).
    float4* __restrict__ so_w = (float4*)(so + wave * WAVE_SLICE_F + lane * 36);
#pragma unroll
    for (int j = 0; j < 9; ++j) {
        so_w[j] = make_float4(o36[j * 4 + 0], o36[j * 4 + 1],
                              o36[j * 4 + 2], o36[j * 4 + 3]);
    }

    // Wave-private flush: lane reads contiguous float4s written by its own wave
    // (same-wave LDS visibility = lgkmcnt, no barrier needed). 9 iters exactly.
    const float4* __restrict__ so_r = (const float4*)(so + wave * WAVE_SLICE_F);
    float4* __restrict__ outv = (float4*)(out + (size_t)wavePair * 9);
#pragma unroll
    for (int k = 0; k < 9; ++k) {
        outv[lane + 64 * k] = so_r[lane + 64 * k];
    }
}

extern "C" void kernel_launch(void* const* d_in, const int* in_sizes, int n_in,
                              void* d_out, int out_size, void* d_ws, size_t ws_size,
                              hipStream_t stream) {
    const float* x = (const float*)d_in[0];   // 27 floats
    const float* w = (const float*)d_in[1];   // 2048*2048*3 floats
    float* out = (float*)d_out;               // 2048*2048*9 floats

    const int pairs  = 2048 * 2048;                 // 4,194,304
    const int blocks = pairs / PAIRS_PER_BLOCK;     // 4096, exact cover
    gf_kernel<<<blocks, 256, 0, stream>>>(x, w, out);
}